// Round 3
// baseline (253.179 us; speedup 1.0000x reference)
//
#include <hip/hip_runtime.h>

#define BLK 256
#define BATCH 8192

// ---- CNOT-ring permutation P (verified in round 1): y = P x ----
// y_p = x_p ^ ... ^ x_11 (p<=10); y_11 = x_0 ^ ... ^ x_10
struct M12 { unsigned r[12]; };
constexpr M12 mp_matrix() {
  M12 m{};
  for (int p = 0; p <= 10; ++p) m.r[p] = (0xFFFu >> p) << p;
  m.r[11] = 0x7FFu;
  return m;
}
constexpr M12 MP = mp_matrix();

constexpr unsigned pmap_c(unsigned v) {   // P(v), compile-time
  unsigned out = 0;
  for (int p = 0; p < 12; ++p)
    out |= (unsigned)(__builtin_popcount(v & MP.r[p]) & 1) << p;
  return out;
}
static_assert(pmap_c(0x800u) == 0x7FFu, "col 11 of P");
static_assert(pmap_c(1u) == 0x801u, "col 0 of P");

struct PTab { unsigned v[32]; };
constexpr PTab make_ptab() {
  PTab t{};
  for (unsigned r = 0; r < 32; ++r) t.v[r] = pmap_c(r);
  return t;
}
constexpr PTab kPT = make_ptab();

__device__ __forceinline__ unsigned pmap_rt(unsigned v) {  // P(v), runtime
  unsigned y = v ^ (v >> 1);
  y ^= y >> 2; y ^= y >> 4; y ^= y >> 8;
  const unsigned b11 = (unsigned)(__popc((int)(v & 0x7FFu)) & 1);
  return (y & 0x7FFu) | (b11 << 11);
}

// ---- gate primitives; state: lane holds amps z=(b<<11)|(lane<<5)|r ----
template<int P>
__device__ __forceinline__ void gate_reg(float (&vr)[32], float (&vi)[32],
                                         const float* __restrict__ g) {
  const float r00=g[0],i00=g[1],r01=g[2],i01=g[3];
  const float r10=g[4],i10=g[5],r11=g[6],i11=g[7];
  #pragma unroll
  for (int r = 0; r < 32; ++r) {
    if (!(r & (1 << P))) {
      const int k = r | (1 << P);
      const float ar=vr[r],ai=vi[r],br=vr[k],bi=vi[k];
      vr[r]=r00*ar-i00*ai+r01*br-i01*bi;
      vi[r]=r00*ai+i00*ar+r01*bi+i01*br;
      vr[k]=r10*ar-i10*ai+r11*br-i11*bi;
      vi[k]=r10*ai+i10*ar+r11*bi+i11*br;
    }
  }
}

template<int K>
__device__ __forceinline__ void gate_lane(float (&vr)[32], float (&vi)[32],
                                          const int lane,
                                          const float* __restrict__ g) {
  const bool hl = ((lane >> K) & 1) != 0;
  const float a0r = hl ? g[6] : g[0], a0i = hl ? g[7] : g[1];  // coeff of own
  const float a1r = hl ? g[4] : g[2], a1i = hl ? g[5] : g[3];  // coeff of partner
  #pragma unroll
  for (int r = 0; r < 32; ++r) {
    const float pr = __shfl_xor(vr[r], 1 << K, 64);
    const float pi = __shfl_xor(vi[r], 1 << K, 64);
    const float ar = vr[r], ai = vi[r];
    vr[r] = a0r*ar - a0i*ai + a1r*pr - a1i*pi;
    vi[r] = a0r*ai + a0i*ar + a1r*pi + a1i*pr;
  }
}

// cross-wave gate (bit 11) via chunked ping-pong LDS exchange
__device__ __forceinline__ void gate_wave(float (&vr)[32], float (&vi)[32],
                                          const int b, const int u,
                                          const int lane,
                                          const float* __restrict__ g,
                                          float* sbuf) {
  const float a0r = b ? g[6] : g[0], a0i = b ? g[7] : g[1];
  const float a1r = b ? g[4] : g[2], a1i = b ? g[5] : g[3];
  #pragma unroll
  for (int c = 0; c < 4; ++c) {
    float* reg = sbuf + (c & 1) * 4096 + u * 2048;
    #pragma unroll
    for (int q = 0; q < 8; ++q) {
      reg[(2*q+0)*128 + b*64 + lane] = vr[c*8+q];
      reg[(2*q+1)*128 + b*64 + lane] = vi[c*8+q];
    }
    __syncthreads();
    #pragma unroll
    for (int q = 0; q < 8; ++q) {
      const float pr = reg[(2*q+0)*128 + (b^1)*64 + lane];
      const float pi = reg[(2*q+1)*128 + (b^1)*64 + lane];
      const int r = c*8+q;
      const float ar = vr[r], ai = vi[r];
      vr[r] = a0r*ar - a0i*ai + a1r*pr - a1i*pi;
      vi[r] = a0r*ai + a0i*ar + a1r*pi + a1i*pr;
    }
  }
  __syncthreads();
}

// apply ring permutation: state amp z moves to P(z). XOR-swizzled LDS addrs.
__device__ __forceinline__ void permute_state(float (&vr)[32], float (&vi)[32],
                                              const unsigned ybase, const int u,
                                              float* sbuf) {
  float* buf = sbuf + u * 4096;
  const unsigned pyb = pmap_rt(ybase);
  const unsigned wb = pyb ^ ((pyb >> 5) & 31u);     // P(r) has no bits 5..10
  const unsigned rb = ybase ^ ((ybase >> 5) & 31u);
  #pragma unroll
  for (int r = 0; r < 32; ++r) buf[wb ^ kPT.v[r]] = vr[r];
  __syncthreads();
  #pragma unroll
  for (int r = 0; r < 32; ++r) vr[r] = buf[rb ^ (unsigned)r];
  __syncthreads();
  #pragma unroll
  for (int r = 0; r < 32; ++r) buf[wb ^ kPT.v[r]] = vi[r];
  __syncthreads();
  #pragma unroll
  for (int r = 0; r < 32; ++r) vi[r] = buf[rb ^ (unsigned)r];
  __syncthreads();
}

// one ref-layer of rotations; wire i acts on bit 11-i
template<int LIDX>
__device__ __forceinline__ void apply_layer(float (&vr)[32], float (&vi)[32],
                                            const int b, const int u,
                                            const int lane,
                                            const float* __restrict__ gt,
                                            float* sbuf) {
  gate_wave(vr, vi, b, u, lane, gt + (LIDX*12 + 0)*8, sbuf);   // wire 0, bit 11
  gate_lane<5>(vr, vi, lane, gt + (LIDX*12 + 1)*8);            // wire 1, bit 10
  gate_lane<4>(vr, vi, lane, gt + (LIDX*12 + 2)*8);
  gate_lane<3>(vr, vi, lane, gt + (LIDX*12 + 3)*8);
  gate_lane<2>(vr, vi, lane, gt + (LIDX*12 + 4)*8);
  gate_lane<1>(vr, vi, lane, gt + (LIDX*12 + 5)*8);
  gate_lane<0>(vr, vi, lane, gt + (LIDX*12 + 6)*8);            // wire 6, bit 5
  gate_reg<4>(vr, vi, gt + (LIDX*12 + 7)*8);                   // wire 7, bit 4
  gate_reg<3>(vr, vi, gt + (LIDX*12 + 8)*8);
  gate_reg<2>(vr, vi, gt + (LIDX*12 + 9)*8);
  gate_reg<1>(vr, vi, gt + (LIDX*12 + 10)*8);
  gate_reg<0>(vr, vi, gt + (LIDX*12 + 11)*8);                  // wire 11, bit 0
}

__global__ __launch_bounds__(BLK, 4) void qsim_kernel(
    const float* __restrict__ sr, const float* __restrict__ si,
    const float* __restrict__ wts, const float* __restrict__ hw,
    const float* __restrict__ hb, float* __restrict__ out) {
  __shared__ float sbuf[8192];      // permute bufs (2 x 16KB) / exchange bufs
  __shared__ float gt[24 * 8];      // fused RY*RX gates, ref layers 1..2
  __shared__ float4 qv[2][12];      // per-sample wire vectors after enc+layer0

  const int t = threadIdx.x;
  const int lane = t & 63;
  const int W = t >> 6;
  const int u = W >> 1;             // sample-in-block
  const int b = W & 1;              // wave bit = state bit 11
  const int s = blockIdx.x * 2 + u;

  // Phase A: fused gate table for ref layers 1,2
  if (t < 24) {
    const int l = 1 + t / 12, i = t % 12;
    const float a = wts[(l * 12 + i) * 2 + 0] * 0.5f;
    const float bb = wts[(l * 12 + i) * 2 + 1] * 0.5f;
    float sa, ca, sb, cb;
    sincosf(a, &sa, &ca);
    sincosf(bb, &sb, &cb);
    gt[t*8+0] = cb*ca;  gt[t*8+1] =  sb*sa;
    gt[t*8+2] = -sb*ca; gt[t*8+3] = -cb*sa;
    gt[t*8+4] = sb*ca;  gt[t*8+5] = -cb*sa;
    gt[t*8+6] = cb*ca;  gt[t*8+7] = -sb*sa;
  }
  // Phase B: per-wire vectors q_i = G_layer0 * RY(a)RX(a)|0>
  if (b == 0 && lane < 12) {
    const float ang = atan2f(si[(size_t)s * 4096 + lane],
                             sr[(size_t)s * 4096 + lane]) * 0.5f;
    float sn, cs;
    sincosf(ang, &sn, &cs);
    const float e0r = cs*cs, e0i = sn*sn, e1r = sn*cs, e1i = -sn*cs;
    const float a = wts[lane * 2 + 0] * 0.5f;
    const float bb = wts[lane * 2 + 1] * 0.5f;
    float sa, ca, sb, cb;
    sincosf(a, &sa, &ca);
    sincosf(bb, &sb, &cb);
    const float g00r = cb*ca, g00i = sb*sa, g01r = -sb*ca, g01i = -cb*sa;
    const float g10r = sb*ca, g10i = -cb*sa, g11r = cb*ca, g11i = -sb*sa;
    const float q0r = g00r*e0r - g00i*e0i + g01r*e1r - g01i*e1i;
    const float q0i = g00r*e0i + g00i*e0r + g01r*e1i + g01i*e1r;
    const float q1r = g10r*e0r - g10i*e0i + g11r*e1r - g11i*e1i;
    const float q1i = g10r*e0i + g10i*e0r + g11r*e1i + g11i*e1r;
    qv[u][lane] = make_float4(q0r, q0i, q1r, q1i);
  }
  __syncthreads();

  // Phase C: build product state. wire0<->bit11(b), wires1-6<->lane bits 5..0,
  // wires7-11<->reg bits 4..0.
  float vr[32], vi[32];
  {
    const float4* q = qv[u];
    float Lr, Li;
    {
      const float4 q0 = q[0];
      Lr = b ? q0.z : q0.x;
      Li = b ? q0.w : q0.y;
    }
    #pragma unroll
    for (int i = 1; i <= 6; ++i) {
      const float4 qq = q[i];
      const int bit = (lane >> (6 - i)) & 1;
      const float fr = bit ? qq.z : qq.x, fi = bit ? qq.w : qq.y;
      const float nr = Lr*fr - Li*fi, ni = Lr*fi + Li*fr;
      Lr = nr; Li = ni;
    }
    float thr[4], thi[4];
    {
      const float4 q7 = q[7], q8 = q[8];
      #pragma unroll
      for (int m = 0; m < 4; ++m) {
        const float ar = (m & 2) ? q7.z : q7.x, ai = (m & 2) ? q7.w : q7.y;
        const float br = (m & 1) ? q8.z : q8.x, bi = (m & 1) ? q8.w : q8.y;
        const float tr = ar*br - ai*bi, ti = ar*bi + ai*br;
        thr[m] = Lr*tr - Li*ti;
        thi[m] = Lr*ti + Li*tr;
      }
    }
    float tlr[8], tli[8];
    {
      const float4 q9 = q[9], qA = q[10], qB = q[11];
      #pragma unroll
      for (int m = 0; m < 8; ++m) {
        const float ar = (m & 4) ? q9.z : q9.x, ai = (m & 4) ? q9.w : q9.y;
        const float br = (m & 2) ? qA.z : qA.x, bi = (m & 2) ? qA.w : qA.y;
        const float cr = (m & 1) ? qB.z : qB.x, ci = (m & 1) ? qB.w : qB.y;
        const float t1r = ar*br - ai*bi, t1i = ar*bi + ai*br;
        tlr[m] = t1r*cr - t1i*ci;
        tli[m] = t1r*ci + t1i*cr;
      }
    }
    #pragma unroll
    for (int r = 0; r < 32; ++r) {
      vr[r] = thr[r>>3]*tlr[r&7] - thi[r>>3]*tli[r&7];
      vi[r] = thr[r>>3]*tli[r&7] + thi[r>>3]*tlr[r&7];
    }
  }

  const unsigned ybase = ((unsigned)b << 11) | ((unsigned)lane << 5);

  // ring1 -> layer1 rots -> ring2 -> layer2 rots (ring3 folded into measure)
  permute_state(vr, vi, ybase, u, sbuf);
  apply_layer<0>(vr, vi, b, u, lane, gt, sbuf);
  permute_state(vr, vi, ybase, u, sbuf);
  apply_layer<1>(vr, vi, b, u, lane, gt, sbuf);

  // Phase E: y = sum_z |B_z|^2 * w(P z) + bias
  float hp[12];
  #pragma unroll
  for (int i = 0; i < 12; ++i) {
    const unsigned R = MP.r[11 - i];
    const float h = hw[i];
    hp[i] = (__popc((int)(ybase & R)) & 1) ? -h : h;
  }
  float acc = 0.f;
  #pragma unroll
  for (int r = 0; r < 32; ++r) {
    float wgt = 0.f;
    #pragma unroll
    for (int i = 0; i < 12; ++i)
      wgt += (__builtin_popcount((unsigned)r & (MP.r[11 - i] & 31u)) & 1)
                 ? -hp[i] : hp[i];
    acc += (vr[r]*vr[r] + vi[r]*vi[r]) * wgt;
  }
  #pragma unroll
  for (int off = 1; off < 64; off <<= 1) acc += __shfl_xor(acc, off, 64);

  __syncthreads();                      // sbuf reuse guard
  if (b == 1 && lane == 0) sbuf[u] = acc;
  __syncthreads();
  if (b == 0 && lane == 0) out[s] = acc + sbuf[u] + hb[0];
}

extern "C" void kernel_launch(void* const* d_in, const int* in_sizes, int n_in,
                              void* d_out, int out_size, void* d_ws, size_t ws_size,
                              hipStream_t stream) {
  const float* sr  = (const float*)d_in[0];
  const float* si  = (const float*)d_in[1];
  const float* wts = (const float*)d_in[2];
  const float* hw  = (const float*)d_in[3];
  const float* hb  = (const float*)d_in[4];
  float* out = (float*)d_out;
  qsim_kernel<<<BATCH / 2, BLK, 0, stream>>>(sr, si, wts, hw, hb, out);
}

// Round 5
// 190.786 us; speedup vs baseline: 1.3270x; 1.3270x over previous
//
#include <hip/hip_runtime.h>

typedef float v2f __attribute__((ext_vector_type(2)));
typedef __fp16 h2v __attribute__((ext_vector_type(2)));
typedef __fp16 h4v __attribute__((ext_vector_type(4)));

#define BLK 256
#define BATCH 8192

// ================= GF(2) 12x12 compile-time machinery =================
struct M12 { unsigned r[12]; };

constexpr M12 mp_matrix() {
  // CNOT-ring permutation y = P x (verified rounds 1-3):
  // y_p = x_p ^ ... ^ x_11 (p<=10); y_11 = x_0 ^ ... ^ x_10
  M12 m{};
  for (int p = 0; p <= 10; ++p) m.r[p] = (0xFFFu >> p) << p;
  m.r[11] = 0x7FFu;
  return m;
}
constexpr M12 MP = mp_matrix();

constexpr unsigned mv(const M12 m, unsigned v) {   // y = M v (rows)
  unsigned y = 0;
  for (int p = 0; p < 12; ++p)
    y |= (unsigned)(__builtin_popcount(m.r[p] & v) & 1) << p;
  return y;
}
constexpr M12 mmul(const M12 a, const M12 b) {     // c(x) = a(b(x))
  M12 c{};
  for (int p = 0; p < 12; ++p) {
    unsigned acc = 0;
    for (int q = 0; q < 12; ++q)
      if ((a.r[p] >> q) & 1u) acc ^= b.r[q];
    c.r[p] = acc;
  }
  return c;
}
constexpr M12 minv(const M12 a0) {                 // Gauss-Jordan over GF(2)
  unsigned a[12] = {}, v[12] = {};
  for (int i = 0; i < 12; ++i) { a[i] = a0.r[i]; v[i] = 1u << i; }
  for (int c = 0; c < 12; ++c) {
    int piv = c;
    while (!((a[piv] >> c) & 1u)) ++piv;           // OOB here => constexpr error (singular)
    unsigned ta = a[piv], tv = v[piv];
    a[piv] = a[c]; v[piv] = v[c]; a[c] = ta; v[c] = tv;
    for (int r2 = 0; r2 < 12; ++r2)
      if (r2 != c && ((a[r2] >> c) & 1u)) { a[r2] ^= a[c]; v[r2] ^= v[c]; }
  }
  M12 out{};
  for (int i = 0; i < 12; ++i) out.r[i] = v[i];
  return out;
}
constexpr unsigned colq(const M12 m, int q) {
  unsigned c = 0;
  for (int p = 0; p < 12; ++p) c |= ((m.r[p] >> q) & 1u) << p;
  return c;
}
constexpr M12 from_cols(const unsigned (&c)[12]) {
  M12 m{};
  for (int p = 0; p < 12; ++p) {
    unsigned row = 0;
    for (int j = 0; j < 12; ++j) row |= ((c[j] >> p) & 1u) << j;
    m.r[p] = row;
  }
  return m;
}
constexpr M12 mk_id() { M12 m{}; for (int p = 0; p < 12; ++p) m.r[p] = 1u << p; return m; }
constexpr M12 MID = mk_id();
constexpr M12 MPI = minv(MP);

constexpr bool meq(const M12 a, const M12 b) {
  for (int p = 0; p < 12; ++p) if (a.r[p] != b.r[p]) return false;
  return true;
}
static_assert(meq(mmul(MP, MPI), MID), "P inverse");

struct Frame { M12 A, Ai; };
constexpr Frame FID{MID, MID};
// ring absorb: logical labels x -> P x at fixed positions
constexpr Frame absorb(const Frame f) { return Frame{ mmul(MP, f.A), mmul(f.Ai, MPI) }; }
// data movement p -> tau(p): A' = A o tau^-1
constexpr Frame apply_tau(const Frame f, const M12 t) {
  return Frame{ mmul(f.A, minv(t)), mmul(t, f.Ai) };
}

constexpr void complete12(unsigned (&V)[12], int n) {
  unsigned ech[12] = {};
  for (int i = 0; i < n; ++i) {
    unsigned x = V[i];
    for (int bb = 11; bb >= 0; --bb) {
      if (((x >> bb) & 1u) == 0u) continue;
      if (ech[bb]) { x ^= ech[bb]; }
      else { ech[bb] = x; break; }
    }
  }
  int cnt = n;
  for (unsigned j = 0; j < 12 && cnt < 12; ++j) {
    unsigned x = 1u << j;
    bool placed = false;
    for (int bb = 11; bb >= 0 && !placed; --bb) {
      if (((x >> bb) & 1u) == 0u) continue;
      if (ech[bb]) { x ^= ech[bb]; }
      else { ech[bb] = x; placed = true; }
    }
    if (placed) { V[cnt] = 1u << j; ++cnt; }
  }
}
// tau with tau(mask_q) = target_q for the group, completed to a bijection
constexpr M12 make_tau(const Frame f, const int* qs, const unsigned* tg, int n) {
  unsigned S[12] = {}, D[12] = {};
  for (int i = 0; i < n; ++i) { S[i] = colq(f.Ai, qs[i]); D[i] = tg[i]; }
  complete12(S, n); complete12(D, n);
  return mmul(from_cols(D), minv(from_cols(S)));
}
constexpr bool chk_group(const Frame f, const int* qs, const unsigned* tg, int n) {
  for (int i = 0; i < n; ++i) if (colq(f.Ai, qs[i]) != tg[i]) return false;
  return true;
}

// groups: logical bits -> reg-span targets
constexpr int QA[5] = {11, 10, 9, 8, 7};
constexpr int QB[5] = {6, 5, 4, 3, 2};
constexpr int QC[2] = {1, 0};
constexpr unsigned T5[5] = {16u, 8u, 4u, 2u, 1u};
constexpr unsigned T2v[2] = {2u, 1u};

constexpr Frame F1  = absorb(FID);                 // ring 1 absorbed
constexpr M12  S2a = make_tau(F1,  QA, T5, 5);
constexpr Frame F2a = apply_tau(F1, S2a);
constexpr M12  S2b = make_tau(F2a, QB, T5, 5);
constexpr Frame F2b = apply_tau(F2a, S2b);
constexpr M12  S2c = make_tau(F2b, QC, T2v, 2);
constexpr Frame F2c = apply_tau(F2b, S2c);
constexpr Frame F3  = absorb(F2c);                 // ring 2 absorbed
constexpr M12  S3a = make_tau(F3,  QA, T5, 5);
constexpr Frame F3a = apply_tau(F3, S3a);
constexpr M12  S3b = make_tau(F3a, QB, T5, 5);
constexpr Frame F3b = apply_tau(F3a, S3b);
constexpr M12  S3c = make_tau(F3b, QC, T2v, 2);
constexpr Frame F3c = apply_tau(F3b, S3c);
constexpr Frame F4  = absorb(F3c);                 // ring 3 absorbed; measure frame

static_assert(chk_group(F2a, QA, T5, 5), "G2a");
static_assert(chk_group(F2b, QB, T5, 5), "G2b");
static_assert(chk_group(F2c, QC, T2v, 2), "G2c");
static_assert(chk_group(F3a, QA, T5, 5), "G3a");
static_assert(chk_group(F3b, QB, T5, 5), "G3b");
static_assert(chk_group(F3c, QC, T2v, 2), "G3c");

// ---- runtime tau tables (addresses pre-swizzled; swz is GF(2)-linear) ----
constexpr unsigned swz(unsigned s) {
  return s ^ (((s >> 5) & 15u) << 1) ^ (((s >> 9) & 7u) << 1);
}
struct TauRT { unsigned wc[32]; unsigned cb[6]; unsigned c11; };
constexpr TauRT mk_rt(const M12 T) {
  TauRT t{};
  for (unsigned r = 0; r < 32; ++r) t.wc[r] = swz(mv(T, r));
  for (int k = 0; k < 6; ++k) t.cb[k] = swz(mv(T, 1u << (5 + k)));
  t.c11 = swz(mv(T, 1u << 11));
  return t;
}
constexpr TauRT RT[6] = { mk_rt(S2a), mk_rt(S2b), mk_rt(S2c),
                          mk_rt(S3a), mk_rt(S3b), mk_rt(S3c) };

// ================= device primitives =================
// sigma pass: amp at pos p moves to tau(p); f16x2 staging (scatter b32 write,
// linear b64 read).
template<int TI>
__device__ __forceinline__ void sigma_pass(v2f (&xr)[16], v2f (&xi)[16],
                                           unsigned* sb, const int lane,
                                           const int b, const unsigned rb) {
  unsigned wb = b ? RT[TI].c11 : 0u;
  #pragma unroll
  for (int k = 0; k < 6; ++k)
    wb ^= ((lane >> k) & 1) ? RT[TI].cb[k] : 0u;
  h2v* sh = (h2v*)sb;
  #pragma unroll
  for (int pp = 0; pp < 16; ++pp) {
    sh[wb ^ RT[TI].wc[2 * pp]]     = __builtin_amdgcn_cvt_pkrtz(xr[pp].x, xi[pp].x);
    sh[wb ^ RT[TI].wc[2 * pp + 1]] = __builtin_amdgcn_cvt_pkrtz(xr[pp].y, xi[pp].y);
  }
  __syncthreads();
  #pragma unroll
  for (int pp = 0; pp < 16; ++pp) {
    const h4v hv = *(const h4v*)(sb + (rb ^ (unsigned)(2 * pp)));
    xr[pp] = (v2f){(float)hv[0], (float)hv[2]};
    xi[pp] = (v2f){(float)hv[1], (float)hv[3]};
  }
  __syncthreads();
}

// register gate on reg-span MASK with full role row RROW (side = parity(p&R))
template<unsigned MASK, unsigned RROW>
__device__ __forceinline__ void gate_apply(v2f (&xr)[16], v2f (&xi)[16],
                                           const int lane, const int b,
                                           const float* __restrict__ g) {
  static_assert((__builtin_popcount(MASK & RROW) & 1) == 1, "role/mask dot");
  constexpr unsigned R5 = RROW & 31u;
  constexpr int c0f = (int)(RROW & 1u);
  const float4 gA = *(const float4*)(g);       // g00r g00i g01r g01i
  const float4 gB = *(const float4*)(g + 4);   // g10r g10i g11r g11i
  const int hl = (__popc((unsigned)lane & ((RROW >> 5) & 63u)) +
                  (b & (int)((RROW >> 11) & 1u))) & 1;
  const int t0 = hl, tA = hl ^ c0f;
  // set s: pattern for packs with base-side s. own(side)=side?g11:g00, par=side?g10:g01
  v2f oR[2], oI[2], pR[2], pI[2];
  oR[0] = (v2f){ t0 ? gB.z : gA.x, tA ? gB.z : gA.x };
  oI[0] = (v2f){ t0 ? gB.w : gA.y, tA ? gB.w : gA.y };
  pR[0] = (v2f){ t0 ? gB.x : gA.z, tA ? gB.x : gA.z };
  pI[0] = (v2f){ t0 ? gB.y : gA.w, tA ? gB.y : gA.w };
  oR[1] = (v2f){ t0 ? gA.x : gB.z, tA ? gA.x : gB.z };
  oI[1] = (v2f){ t0 ? gA.y : gB.w, tA ? gA.y : gB.w };
  pR[1] = (v2f){ t0 ? gA.z : gB.x, tA ? gA.z : gB.x };
  pI[1] = (v2f){ t0 ? gA.w : gB.y, tA ? gA.w : gB.y };

  if constexpr (MASK == 1u) {
    static_assert(c0f == 1, "bit0 gate needs R bit0");
    #pragma unroll
    for (int pp = 0; pp < 16; ++pp) {
      const int sp = __builtin_popcount((unsigned)(2 * pp) & R5) & 1;
      const v2f ar = xr[pp], ai = xi[pp];
      const v2f br = __builtin_shufflevector(ar, ar, 1, 0);
      const v2f bi = __builtin_shufflevector(ai, ai, 1, 0);
      xr[pp] = oR[sp] * ar - oI[sp] * ai + pR[sp] * br - pI[sp] * bi;
      xi[pp] = oR[sp] * ai + oI[sp] * ar + pR[sp] * bi + pI[sp] * br;
    }
  } else {
    constexpr int MB = (int)(MASK >> 1);
    #pragma unroll
    for (int pp = 0; pp < 16; ++pp) {
      if ((pp & MB) == 0) {
        const int qq = pp | MB;
        const int sp = __builtin_popcount((unsigned)(2 * pp) & R5) & 1;
        const int sq = sp ^ 1;
        const v2f ar = xr[pp], ai = xi[pp], br = xr[qq], bi = xi[qq];
        xr[pp] = oR[sp] * ar - oI[sp] * ai + pR[sp] * br - pI[sp] * bi;
        xi[pp] = oR[sp] * ai + oI[sp] * ar + pR[sp] * bi + pI[sp] * br;
        xr[qq] = oR[sq] * br - oI[sq] * bi + pR[sq] * ar - pI[sq] * ai;
        xi[qq] = oR[sq] * bi + oI[sq] * br + pR[sq] * ai + pI[sq] * ar;
      }
    }
  }
}

// ================= kernel =================
__global__ __launch_bounds__(BLK, 4) void qsim_kernel(
    const float* __restrict__ sr, const float* __restrict__ si,
    const float* __restrict__ wts, const float* __restrict__ hw,
    const float* __restrict__ hb, float* __restrict__ out) {
  __shared__ unsigned sbuf[2][4096];   // 32 KB: per-sample f16x2 sigma staging
  __shared__ float gt[24 * 8];         // fused RY*RX gates, ref layers 1..2
  __shared__ float4 qv[2][12];         // per-sample wire vectors after enc+layer0
  __shared__ float xacc[2];

  const int t = threadIdx.x;
  const int lane = t & 63;
  const int W = t >> 6;
  const int u = W >> 1;                // sample in block
  const int b = W & 1;                 // wave = position bit 11
  const int s = blockIdx.x * 2 + u;

  // Phase A: fused gate table G = RY(b)*RX(a) for ref layers 1,2
  if (t < 24) {
    const int l = 1 + t / 12, i = t % 12;
    const float a  = wts[(l * 12 + i) * 2 + 0] * 0.5f;
    const float bb = wts[(l * 12 + i) * 2 + 1] * 0.5f;
    float sa, ca, sb2, cb;
    sincosf(a, &sa, &ca);
    sincosf(bb, &sb2, &cb);
    gt[t * 8 + 0] = cb * ca;   gt[t * 8 + 1] =  sb2 * sa;
    gt[t * 8 + 2] = -sb2 * ca; gt[t * 8 + 3] = -cb * sa;
    gt[t * 8 + 4] = sb2 * ca;  gt[t * 8 + 5] = -cb * sa;
    gt[t * 8 + 6] = cb * ca;   gt[t * 8 + 7] = -sb2 * sa;
  }
  // Phase B: per-wire vectors q_i = G_layer0 * RY(a)RX(a)|0>
  if (b == 0 && lane < 12) {
    const float ang = atan2f(si[(size_t)s * 4096 + lane],
                             sr[(size_t)s * 4096 + lane]) * 0.5f;
    float sn, cs;
    sincosf(ang, &sn, &cs);
    const float e0r = cs * cs, e0i = sn * sn, e1r = sn * cs, e1i = -sn * cs;
    const float a  = wts[lane * 2 + 0] * 0.5f;
    const float bb = wts[lane * 2 + 1] * 0.5f;
    float sa, ca, sb2, cb;
    sincosf(a, &sa, &ca);
    sincosf(bb, &sb2, &cb);
    const float g00r = cb * ca,  g00i = sb2 * sa, g01r = -sb2 * ca, g01i = -cb * sa;
    const float g10r = sb2 * ca, g10i = -cb * sa, g11r = cb * ca,   g11i = -sb2 * sa;
    const float q0r = g00r * e0r - g00i * e0i + g01r * e1r - g01i * e1i;
    const float q0i = g00r * e0i + g00i * e0r + g01r * e1i + g01i * e1r;
    const float q1r = g10r * e0r - g10i * e0i + g11r * e1r - g11i * e1i;
    const float q1i = g10r * e0i + g10i * e0r + g11r * e1i + g11i * e1r;
    qv[u][lane] = make_float4(q0r, q0i, q1r, q1i);
  }
  __syncthreads();

  // Phase C: build product state (frame = identity: wire0<->bit11, wires1-6
  // <->lane bits 5..0, wires7-11<->reg bits 4..0). Packed along amp bit 0.
  v2f xr[16], xi[16];
  {
    const float4* q = qv[u];
    float Lr, Li;
    { const float4 q0 = q[0]; Lr = b ? q0.z : q0.x; Li = b ? q0.w : q0.y; }
    #pragma unroll
    for (int i = 1; i <= 6; ++i) {
      const float4 qq = q[i];
      const int bit = (lane >> (6 - i)) & 1;
      const float fr = bit ? qq.z : qq.x, fi = bit ? qq.w : qq.y;
      const float nr = Lr * fr - Li * fi, ni = Lr * fi + Li * fr;
      Lr = nr; Li = ni;
    }
    float thr[4], thi[4];
    {
      const float4 q7 = q[7], q8 = q[8];
      #pragma unroll
      for (int m = 0; m < 4; ++m) {
        const float ar = (m & 2) ? q7.z : q7.x, ai = (m & 2) ? q7.w : q7.y;
        const float br = (m & 1) ? q8.z : q8.x, bi = (m & 1) ? q8.w : q8.y;
        const float tr = ar * br - ai * bi, ti = ar * bi + ai * br;
        thr[m] = Lr * tr - Li * ti; thi[m] = Lr * ti + Li * tr;
      }
    }
    float tlr[8], tli[8];
    {
      const float4 q9 = q[9], qA = q[10], qB = q[11];
      #pragma unroll
      for (int m = 0; m < 8; ++m) {
        const float ar = (m & 4) ? q9.z : q9.x, ai = (m & 4) ? q9.w : q9.y;
        const float br = (m & 2) ? qA.z : qA.x, bi = (m & 2) ? qA.w : qA.y;
        const float cr = (m & 1) ? qB.z : qB.x, ci = (m & 1) ? qB.w : qB.y;
        const float t1r = ar * br - ai * bi, t1i = ar * bi + ai * br;
        tlr[m] = t1r * cr - t1i * ci; tli[m] = t1r * ci + t1i * cr;
      }
    }
    #pragma unroll
    for (int pp = 0; pp < 16; ++pp) {
      const int h = pp >> 2, l = (pp & 3) * 2;
      const v2f TLr = (v2f){tlr[l], tlr[l + 1]}, TLi = (v2f){tli[l], tli[l + 1]};
      const v2f Hr = (v2f){thr[h], thr[h]}, Hi = (v2f){thi[h], thi[h]};
      xr[pp] = Hr * TLr - Hi * TLi;
      xi[pp] = Hr * TLi + Hi * TLr;
    }
  }

  unsigned* sb = sbuf[u];
  const unsigned ybase = ((unsigned)b << 11) | ((unsigned)lane << 5);
  const unsigned rb = swz(ybase);

  // ======= layer 2 (ring1 pre-absorbed into frames) =======
  sigma_pass<0>(xr, xi, sb, lane, b, rb);
  gate_apply<16u, F2a.A.r[11]>(xr, xi, lane, b, gt + 0 * 8);
  gate_apply< 8u, F2a.A.r[10]>(xr, xi, lane, b, gt + 1 * 8);
  gate_apply< 4u, F2a.A.r[ 9]>(xr, xi, lane, b, gt + 2 * 8);
  gate_apply< 2u, F2a.A.r[ 8]>(xr, xi, lane, b, gt + 3 * 8);
  gate_apply< 1u, F2a.A.r[ 7]>(xr, xi, lane, b, gt + 4 * 8);
  sigma_pass<1>(xr, xi, sb, lane, b, rb);
  gate_apply<16u, F2b.A.r[ 6]>(xr, xi, lane, b, gt + 5 * 8);
  gate_apply< 8u, F2b.A.r[ 5]>(xr, xi, lane, b, gt + 6 * 8);
  gate_apply< 4u, F2b.A.r[ 4]>(xr, xi, lane, b, gt + 7 * 8);
  gate_apply< 2u, F2b.A.r[ 3]>(xr, xi, lane, b, gt + 8 * 8);
  gate_apply< 1u, F2b.A.r[ 2]>(xr, xi, lane, b, gt + 9 * 8);
  sigma_pass<2>(xr, xi, sb, lane, b, rb);
  gate_apply< 2u, F2c.A.r[ 1]>(xr, xi, lane, b, gt + 10 * 8);
  gate_apply< 1u, F2c.A.r[ 0]>(xr, xi, lane, b, gt + 11 * 8);
  // ======= layer 3 (ring2 absorbed) =======
  sigma_pass<3>(xr, xi, sb, lane, b, rb);
  gate_apply<16u, F3a.A.r[11]>(xr, xi, lane, b, gt + 12 * 8);
  gate_apply< 8u, F3a.A.r[10]>(xr, xi, lane, b, gt + 13 * 8);
  gate_apply< 4u, F3a.A.r[ 9]>(xr, xi, lane, b, gt + 14 * 8);
  gate_apply< 2u, F3a.A.r[ 8]>(xr, xi, lane, b, gt + 15 * 8);
  gate_apply< 1u, F3a.A.r[ 7]>(xr, xi, lane, b, gt + 16 * 8);
  sigma_pass<4>(xr, xi, sb, lane, b, rb);
  gate_apply<16u, F3b.A.r[ 6]>(xr, xi, lane, b, gt + 17 * 8);
  gate_apply< 8u, F3b.A.r[ 5]>(xr, xi, lane, b, gt + 18 * 8);
  gate_apply< 4u, F3b.A.r[ 4]>(xr, xi, lane, b, gt + 19 * 8);
  gate_apply< 2u, F3b.A.r[ 3]>(xr, xi, lane, b, gt + 20 * 8);
  gate_apply< 1u, F3b.A.r[ 2]>(xr, xi, lane, b, gt + 21 * 8);
  sigma_pass<5>(xr, xi, sb, lane, b, rb);
  gate_apply< 2u, F3c.A.r[ 1]>(xr, xi, lane, b, gt + 22 * 8);
  gate_apply< 1u, F3c.A.r[ 0]>(xr, xi, lane, b, gt + 23 * 8);

  // ======= measure: y = sum |amp|^2 * w(F4.A * p) + bias (ring3 absorbed) ===
  float hp[12];
  #pragma unroll
  for (int i = 0; i < 12; ++i) {
    const unsigned R = F4.A.r[11 - i];
    const int sg = (__popc((unsigned)lane & ((R >> 5) & 63u)) +
                    (b & (int)((R >> 11) & 1u))) & 1;
    const float h = hw[i];
    hp[i] = sg ? -h : h;
  }
  float C = 0.f;
  #pragma unroll
  for (int i = 0; i < 12; ++i)
    if ((F4.A.r[11 - i] & 31u) == 0u) C += hp[i];
  v2f acc = (v2f){0.f, 0.f};
  #pragma unroll
  for (int pp = 0; pp < 16; ++pp) {
    float w0 = C, w1 = C;
    #pragma unroll
    for (int i = 0; i < 12; ++i) {
      const unsigned RL = F4.A.r[11 - i] & 31u;
      if (RL != 0u) {
        w0 += (__builtin_popcount((unsigned)(2 * pp) & RL) & 1) ? -hp[i] : hp[i];
        w1 += (__builtin_popcount((unsigned)(2 * pp + 1) & RL) & 1) ? -hp[i] : hp[i];
      }
    }
    const v2f mag = xr[pp] * xr[pp] + xi[pp] * xi[pp];
    acc += mag * (v2f){w0, w1};
  }
  float accs = acc.x + acc.y;
  #pragma unroll
  for (int off = 1; off < 64; off <<= 1) accs += __shfl_xor(accs, off, 64);

  if (b == 1 && lane == 0) xacc[u] = accs;
  __syncthreads();
  if (b == 0 && lane == 0) out[s] = accs + xacc[u] + hb[0];
}

extern "C" void kernel_launch(void* const* d_in, const int* in_sizes, int n_in,
                              void* d_out, int out_size, void* d_ws, size_t ws_size,
                              hipStream_t stream) {
  const float* sr  = (const float*)d_in[0];
  const float* si  = (const float*)d_in[1];
  const float* wts = (const float*)d_in[2];
  const float* hw  = (const float*)d_in[3];
  const float* hb  = (const float*)d_in[4];
  float* out = (float*)d_out;
  qsim_kernel<<<BATCH / 2, BLK, 0, stream>>>(sr, si, wts, hw, hb, out);
}

// Round 6
// 160.523 us; speedup vs baseline: 1.5772x; 1.1885x over previous
//
#include <hip/hip_runtime.h>

typedef float v2f __attribute__((ext_vector_type(2)));
typedef __fp16 h2v __attribute__((ext_vector_type(2)));
typedef __fp16 h4v __attribute__((ext_vector_type(4)));

#define BLK 256
#define BATCH 8192

// ================= GF(2) 12x12 compile-time machinery =================
struct M12 { unsigned r[12]; };

constexpr M12 mp_matrix() {
  // CNOT-ring permutation y = P x (verified rounds 1-5):
  // y_p = x_p ^ ... ^ x_11 (p<=10); y_11 = x_0 ^ ... ^ x_10
  M12 m{};
  for (int p = 0; p <= 10; ++p) m.r[p] = (0xFFFu >> p) << p;
  m.r[11] = 0x7FFu;
  return m;
}
constexpr M12 MP = mp_matrix();

constexpr unsigned mv(const M12 m, unsigned v) {   // y = M v
  unsigned y = 0;
  for (int p = 0; p < 12; ++p)
    y |= (unsigned)(__builtin_popcount(m.r[p] & v) & 1) << p;
  return y;
}
constexpr M12 mmul(const M12 a, const M12 b) {     // c(x) = a(b(x))
  M12 c{};
  for (int p = 0; p < 12; ++p) {
    unsigned acc = 0;
    for (int q = 0; q < 12; ++q)
      if ((a.r[p] >> q) & 1u) acc ^= b.r[q];
    c.r[p] = acc;
  }
  return c;
}
constexpr M12 minv(const M12 a0) {                 // Gauss-Jordan over GF(2)
  unsigned a[12] = {}, v[12] = {};
  for (int i = 0; i < 12; ++i) { a[i] = a0.r[i]; v[i] = 1u << i; }
  for (int c = 0; c < 12; ++c) {
    int piv = c;
    while (!((a[piv] >> c) & 1u)) ++piv;
    unsigned ta = a[piv], tv = v[piv];
    a[piv] = a[c]; v[piv] = v[c]; a[c] = ta; v[c] = tv;
    for (int r2 = 0; r2 < 12; ++r2)
      if (r2 != c && ((a[r2] >> c) & 1u)) { a[r2] ^= a[c]; v[r2] ^= v[c]; }
  }
  M12 out{};
  for (int i = 0; i < 12; ++i) out.r[i] = v[i];
  return out;
}
constexpr unsigned colq(const M12 m, int q) {
  unsigned c = 0;
  for (int p = 0; p < 12; ++p) c |= ((m.r[p] >> q) & 1u) << p;
  return c;
}
constexpr M12 from_cols(const unsigned (&c)[12]) {
  M12 m{};
  for (int p = 0; p < 12; ++p) {
    unsigned row = 0;
    for (int j = 0; j < 12; ++j) row |= ((c[j] >> p) & 1u) << j;
    m.r[p] = row;
  }
  return m;
}
constexpr M12 mk_id() { M12 m{}; for (int p = 0; p < 12; ++p) m.r[p] = 1u << p; return m; }
constexpr M12 MID = mk_id();
constexpr M12 MPI = minv(MP);

constexpr bool meq(const M12 a, const M12 b) {
  for (int p = 0; p < 12; ++p) if (a.r[p] != b.r[p]) return false;
  return true;
}
static_assert(meq(mmul(MP, MPI), MID), "P inverse");

struct Frame { M12 A, Ai; };
constexpr Frame FID{MID, MID};
constexpr Frame absorb(const Frame f) { return Frame{ mmul(MP, f.A), mmul(f.Ai, MPI) }; }
constexpr Frame apply_tau(const Frame f, const M12 t) {
  return Frame{ mmul(f.A, minv(t)), mmul(t, f.Ai) };
}

constexpr void complete12(unsigned (&V)[12], int n) {
  unsigned ech[12] = {};
  for (int i = 0; i < n; ++i) {
    unsigned x = V[i];
    for (int bb = 11; bb >= 0; --bb) {
      if (((x >> bb) & 1u) == 0u) continue;
      if (ech[bb]) { x ^= ech[bb]; }
      else { ech[bb] = x; break; }
    }
  }
  int cnt = n;
  for (unsigned j = 0; j < 12 && cnt < 12; ++j) {
    unsigned x = 1u << j;
    bool placed = false;
    for (int bb = 11; bb >= 0 && !placed; --bb) {
      if (((x >> bb) & 1u) == 0u) continue;
      if (ech[bb]) { x ^= ech[bb]; }
      else { ech[bb] = x; placed = true; }
    }
    if (placed) { V[cnt] = 1u << j; ++cnt; }
  }
}
constexpr M12 make_tau(const Frame f, const int* qs, const unsigned* tg, int n) {
  unsigned S[12] = {}, D[12] = {};
  for (int i = 0; i < n; ++i) { S[i] = colq(f.Ai, qs[i]); D[i] = tg[i]; }
  complete12(S, n); complete12(D, n);
  return mmul(from_cols(D), minv(from_cols(S)));
}
constexpr bool chk_group(const Frame f, const int* qs, const unsigned* tg, int n) {
  for (int i = 0; i < n; ++i) if (colq(f.Ai, qs[i]) != tg[i]) return false;
  return true;
}

// groups: 4 logical qubits -> local-index targets {8,4,2,1} (bit0 = pack)
constexpr int QA[4] = {11, 10, 9, 8};
constexpr int QB[4] = {7, 6, 5, 4};
constexpr int QC[4] = {3, 2, 1, 0};
constexpr unsigned T4[4] = {8u, 4u, 2u, 1u};

constexpr Frame F1  = absorb(FID);                 // ring 1 absorbed
constexpr M12  S2a = make_tau(F1,  QA, T4, 4);
constexpr Frame F2a = apply_tau(F1, S2a);
constexpr M12  S2b = make_tau(F2a, QB, T4, 4);
constexpr Frame F2b = apply_tau(F2a, S2b);
constexpr M12  S2c = make_tau(F2b, QC, T4, 4);
constexpr Frame F2c = apply_tau(F2b, S2c);
constexpr Frame F3  = absorb(F2c);                 // ring 2 absorbed
constexpr M12  S3a = make_tau(F3,  QA, T4, 4);
constexpr Frame F3a = apply_tau(F3, S3a);
constexpr M12  S3b = make_tau(F3a, QB, T4, 4);
constexpr Frame F3b = apply_tau(F3a, S3b);
constexpr M12  S3c = make_tau(F3b, QC, T4, 4);
constexpr Frame F3c = apply_tau(F3b, S3c);
constexpr Frame F4  = absorb(F3c);                 // ring 3 absorbed; measure frame

static_assert(chk_group(F2a, QA, T4, 4), "G2a");
static_assert(chk_group(F2b, QB, T4, 4), "G2b");
static_assert(chk_group(F2c, QC, T4, 4), "G2c");
static_assert(chk_group(F3a, QA, T4, 4), "G3a");
static_assert(chk_group(F3b, QB, T4, 4), "G3b");
static_assert(chk_group(F3c, QC, T4, 4), "G3c");

// ---- swizzle: fold lane bits into addr bits 3..1 (GF(2)-linear, bit0 kept) ----
constexpr unsigned swz(unsigned s) {
  return s ^ (((s >> 5) & 7u) << 1) ^ (((s >> 8) & 3u) << 1);
}
struct TauRT { unsigned wc[16]; unsigned cb[6]; unsigned cw[2]; };
constexpr TauRT mk_rt(const M12 T) {
  TauRT t{};
  for (unsigned r = 0; r < 16; ++r) t.wc[r] = swz(mv(T, r));
  for (int k = 0; k < 6; ++k) t.cb[k] = swz(mv(T, 1u << (4 + k)));
  for (int j = 0; j < 2; ++j) t.cw[j] = swz(mv(T, 1u << (10 + j)));
  return t;
}
constexpr TauRT RT[6] = { mk_rt(S2a), mk_rt(S2b), mk_rt(S2c),
                          mk_rt(S3a), mk_rt(S3b), mk_rt(S3c) };

// ================= device primitives =================
// sigma: amp at position p moves to tau(p); block-wide f16x2 LDS staging.
template<int TI>
__device__ __forceinline__ void sigma_pass(v2f (&xr)[8], v2f (&xi)[8],
                                           unsigned* sb, const int lane,
                                           const int w, const unsigned rb) {
  unsigned wb = 0u;
  #pragma unroll
  for (int k = 0; k < 6; ++k)
    wb ^= ((lane >> k) & 1) ? RT[TI].cb[k] : 0u;
  wb ^= (w & 1) ? RT[TI].cw[0] : 0u;
  wb ^= ((w >> 1) & 1) ? RT[TI].cw[1] : 0u;
  h2v* sh = (h2v*)sb;
  #pragma unroll
  for (int p = 0; p < 8; ++p) {
    sh[wb ^ RT[TI].wc[2 * p]]     = __builtin_amdgcn_cvt_pkrtz(xr[p].x, xi[p].x);
    sh[wb ^ RT[TI].wc[2 * p + 1]] = __builtin_amdgcn_cvt_pkrtz(xr[p].y, xi[p].y);
  }
  __syncthreads();
  #pragma unroll
  for (int p = 0; p < 8; ++p) {
    const h4v hv = *(const h4v*)(sb + (rb ^ (unsigned)(2 * p)));
    xr[p] = (v2f){(float)hv[0], (float)hv[2]};
    xi[p] = (v2f){(float)hv[1], (float)hv[3]};
  }
  __syncthreads();
}

// register gate; fused gate G = [[g, -conj(h)], [h, conj(g)]], gh=(gr,gi,hr,hi).
// Element at local j, side s = parity(j & RROW[3:0]) ^ parity(pbase & RROW[11:4]):
//   n = (s?conj(g):g)*own + (s?h:-conj(h))*partner
//   nr = gr*ar - e*gi*ai - e*hr*br - hi*bi ; ni = gr*ai + e*gi*ar - e*hr*bi + hi*br
// with e = +1 (s=0) / -1 (s=1).
template<unsigned MASK, unsigned RROW>
__device__ __forceinline__ void gate_apply(v2f (&xr)[8], v2f (&xi)[8],
                                           const unsigned pbase,
                                           const float4 gh) {
  static_assert((__builtin_popcount(MASK & RROW) & 1) == 1, "role/mask dot");
  constexpr unsigned R4 = RROW & 15u;
  const int hl = __popc(pbase & (RROW & 0xFF0u)) & 1;
  const float sgn = hl ? -1.f : 1.f;
  const float gr = gh.x, hi = gh.w;
  const v2f eg = (v2f){gh.y, (R4 & 1u) ? -gh.y : gh.y} * sgn;
  const v2f eh = (v2f){gh.z, (R4 & 1u) ? -gh.z : gh.z} * sgn;
  if constexpr (MASK == 1u) {
    static_assert((RROW & 1u) == 1u, "bit0 gate needs role bit0");
    #pragma unroll
    for (int p = 0; p < 8; ++p) {
      const int sp = __builtin_popcount((unsigned)p & (R4 >> 1)) & 1;
      const v2f egp = sp ? -eg : eg, ehp = sp ? -eh : eh;
      const v2f ar = xr[p], ai = xi[p];
      const v2f br = __builtin_shufflevector(ar, ar, 1, 0);
      const v2f bi = __builtin_shufflevector(ai, ai, 1, 0);
      xr[p] = gr * ar - egp * ai - ehp * br - hi * bi;
      xi[p] = gr * ai + egp * ar - ehp * bi + hi * br;
    }
  } else {
    constexpr int MB = (int)(MASK >> 1);     // pack-index mask
    #pragma unroll
    for (int p = 0; p < 8; ++p) {
      if ((p & MB) == 0) {
        const int q = p | MB;
        const int sp = __builtin_popcount((unsigned)p & (R4 >> 1)) & 1;
        const v2f egp = sp ? -eg : eg, ehp = sp ? -eh : eh;
        const v2f arP = xr[p], aiP = xi[p], arQ = xr[q], aiQ = xi[q];
        xr[p] = gr * arP - egp * aiP - ehp * arQ - hi * aiQ;
        xi[p] = gr * aiP + egp * arP - ehp * aiQ + hi * arQ;
        xr[q] = gr * arQ + egp * aiQ + ehp * arP - hi * aiP;
        xi[q] = gr * aiQ - egp * arQ + ehp * aiP + hi * arP;
      }
    }
  }
}

// ================= kernel: one sample per 256-thread block =================
__global__ __launch_bounds__(BLK, 4) void qsim_kernel(
    const float* __restrict__ sr, const float* __restrict__ si,
    const float* __restrict__ wts, const float* __restrict__ hw,
    const float* __restrict__ hb, float* __restrict__ out) {
  __shared__ __align__(16) unsigned sbuf[4096];  // 16 KB f16x2 sigma staging
  __shared__ float4 gt4[24];                     // fused gates (gr,gi,hr,hi)
  __shared__ float4 qv[12];                      // wire vectors after enc+layer0
  __shared__ float xacc[4];

  const int t = threadIdx.x;
  const int lane = t & 63;
  const int w = t >> 6;                          // wave id = position bits 11..10
  const int s = blockIdx.x;

  // Phase A: fused gate table for ref layers 1,2: g=g00, h=g10
  if (t < 24) {
    const int l = 1 + t / 12, i = t % 12;
    const float a  = wts[(l * 12 + i) * 2 + 0] * 0.5f;
    const float bb = wts[(l * 12 + i) * 2 + 1] * 0.5f;
    float sa, ca, sb2, cb;
    sincosf(a, &sa, &ca);
    sincosf(bb, &sb2, &cb);
    gt4[t] = make_float4(cb * ca, sb2 * sa, sb2 * ca, -cb * sa);
  }
  // Phase B: per-wire vectors q_i = G_layer0 * RY(a)RX(a)|0>
  if (t >= 64 && t < 76) {
    const int i = t - 64;
    const float ang = atan2f(si[(size_t)s * 4096 + i],
                             sr[(size_t)s * 4096 + i]) * 0.5f;
    float sn, cs;
    sincosf(ang, &sn, &cs);
    const float e0r = cs * cs, e0i = sn * sn, e1r = sn * cs, e1i = -sn * cs;
    const float a  = wts[i * 2 + 0] * 0.5f;
    const float bb = wts[i * 2 + 1] * 0.5f;
    float sa, ca, sb2, cb;
    sincosf(a, &sa, &ca);
    sincosf(bb, &sb2, &cb);
    const float g00r = cb * ca,  g00i = sb2 * sa, g01r = -sb2 * ca, g01i = -cb * sa;
    const float g10r = sb2 * ca, g10i = -cb * sa, g11r = cb * ca,   g11i = -sb2 * sa;
    const float q0r = g00r * e0r - g00i * e0i + g01r * e1r - g01i * e1i;
    const float q0i = g00r * e0i + g00i * e0r + g01r * e1i + g01i * e1r;
    const float q1r = g10r * e0r - g10i * e0i + g11r * e1r - g11i * e1i;
    const float q1i = g10r * e0i + g10i * e0r + g11r * e1i + g11i * e1r;
    qv[i] = make_float4(q0r, q0i, q1r, q1i);
  }
  __syncthreads();

  // Phase C: product state. wire0<->bit11(w>>1), wire1<->bit10(w&1),
  // wires2-7<->lane bits 5..0, wires8-11<->local bits 3..0 (bit0 = pack).
  v2f xr[8], xi[8];
  {
    const float4* q = qv;
    float Lr, Li;
    { const float4 q0 = q[0]; const int b0 = (w >> 1) & 1;
      Lr = b0 ? q0.z : q0.x; Li = b0 ? q0.w : q0.y; }
    { const float4 q1 = q[1]; const int b1 = w & 1;
      const float fr = b1 ? q1.z : q1.x, fi = b1 ? q1.w : q1.y;
      const float nr = Lr * fr - Li * fi, ni = Lr * fi + Li * fr;
      Lr = nr; Li = ni; }
    #pragma unroll
    for (int i = 2; i <= 7; ++i) {
      const float4 qq = q[i];
      const int bit = (lane >> (7 - i)) & 1;
      const float fr = bit ? qq.z : qq.x, fi = bit ? qq.w : qq.y;
      const float nr = Lr * fr - Li * fi, ni = Lr * fi + Li * fr;
      Lr = nr; Li = ni;
    }
    float LTr[4], LTi[4];
    { const float4 q8 = q[8], q9 = q[9];
      #pragma unroll
      for (int m = 0; m < 4; ++m) {
        const float ar = (m & 2) ? q8.z : q8.x, ai = (m & 2) ? q8.w : q8.y;
        const float br = (m & 1) ? q9.z : q9.x, bi = (m & 1) ? q9.w : q9.y;
        const float tr = ar * br - ai * bi, ti = ar * bi + ai * br;
        LTr[m] = Lr * tr - Li * ti; LTi[m] = Lr * ti + Li * tr;
      } }
    float tabr[4], tabi[4];
    { const float4 qA = q[10], qB = q[11];
      #pragma unroll
      for (int m = 0; m < 4; ++m) {
        const float ar = (m & 2) ? qA.z : qA.x, ai = (m & 2) ? qA.w : qA.y;
        const float br = (m & 1) ? qB.z : qB.x, bi = (m & 1) ? qB.w : qB.y;
        tabr[m] = ar * br - ai * bi; tabi[m] = ar * bi + ai * br;
      } }
    #pragma unroll
    for (int p = 0; p < 8; ++p) {
      const int m = p >> 1, tb = (p & 1) << 1;
      const v2f Tr = (v2f){tabr[tb], tabr[tb + 1]}, Ti = (v2f){tabi[tb], tabi[tb + 1]};
      const v2f Hr = (v2f){LTr[m], LTr[m]}, Hi = (v2f){LTi[m], LTi[m]};
      xr[p] = Hr * Tr - Hi * Ti;
      xi[p] = Hr * Ti + Hi * Tr;
    }
  }

  const unsigned pbase = ((unsigned)w << 10) | ((unsigned)lane << 4);
  const unsigned rb = swz(pbase);

  // ======= layer 2 (ring1 pre-absorbed) =======
  sigma_pass<0>(xr, xi, sbuf, lane, w, rb);
  gate_apply<8u, F2a.A.r[11]>(xr, xi, pbase, gt4[0]);
  gate_apply<4u, F2a.A.r[10]>(xr, xi, pbase, gt4[1]);
  gate_apply<2u, F2a.A.r[ 9]>(xr, xi, pbase, gt4[2]);
  gate_apply<1u, F2a.A.r[ 8]>(xr, xi, pbase, gt4[3]);
  sigma_pass<1>(xr, xi, sbuf, lane, w, rb);
  gate_apply<8u, F2b.A.r[ 7]>(xr, xi, pbase, gt4[4]);
  gate_apply<4u, F2b.A.r[ 6]>(xr, xi, pbase, gt4[5]);
  gate_apply<2u, F2b.A.r[ 5]>(xr, xi, pbase, gt4[6]);
  gate_apply<1u, F2b.A.r[ 4]>(xr, xi, pbase, gt4[7]);
  sigma_pass<2>(xr, xi, sbuf, lane, w, rb);
  gate_apply<8u, F2c.A.r[ 3]>(xr, xi, pbase, gt4[8]);
  gate_apply<4u, F2c.A.r[ 2]>(xr, xi, pbase, gt4[9]);
  gate_apply<2u, F2c.A.r[ 1]>(xr, xi, pbase, gt4[10]);
  gate_apply<1u, F2c.A.r[ 0]>(xr, xi, pbase, gt4[11]);
  // ======= layer 3 (ring2 absorbed) =======
  sigma_pass<3>(xr, xi, sbuf, lane, w, rb);
  gate_apply<8u, F3a.A.r[11]>(xr, xi, pbase, gt4[12]);
  gate_apply<4u, F3a.A.r[10]>(xr, xi, pbase, gt4[13]);
  gate_apply<2u, F3a.A.r[ 9]>(xr, xi, pbase, gt4[14]);
  gate_apply<1u, F3a.A.r[ 8]>(xr, xi, pbase, gt4[15]);
  sigma_pass<4>(xr, xi, sbuf, lane, w, rb);
  gate_apply<8u, F3b.A.r[ 7]>(xr, xi, pbase, gt4[16]);
  gate_apply<4u, F3b.A.r[ 6]>(xr, xi, pbase, gt4[17]);
  gate_apply<2u, F3b.A.r[ 5]>(xr, xi, pbase, gt4[18]);
  gate_apply<1u, F3b.A.r[ 4]>(xr, xi, pbase, gt4[19]);
  sigma_pass<5>(xr, xi, sbuf, lane, w, rb);
  gate_apply<8u, F3c.A.r[ 3]>(xr, xi, pbase, gt4[20]);
  gate_apply<4u, F3c.A.r[ 2]>(xr, xi, pbase, gt4[21]);
  gate_apply<2u, F3c.A.r[ 1]>(xr, xi, pbase, gt4[22]);
  gate_apply<1u, F3c.A.r[ 0]>(xr, xi, pbase, gt4[23]);

  // ======= measure: y = sum |amp|^2 * w(F4.A * pos) + bias =======
  float hp[12];
  #pragma unroll
  for (int i = 0; i < 12; ++i) {
    const unsigned R = F4.A.r[11 - i];
    const float h = hw[i];
    hp[i] = (__popc(pbase & (R & 0xFF0u)) & 1) ? -h : h;
  }
  v2f acc = (v2f){0.f, 0.f};
  #pragma unroll
  for (int p = 0; p < 8; ++p) {
    float w0 = 0.f, w1 = 0.f;
    #pragma unroll
    for (int i = 0; i < 12; ++i) {
      const unsigned RL = F4.A.r[11 - i] & 15u;
      w0 += (__builtin_popcount((unsigned)(2 * p) & RL) & 1) ? -hp[i] : hp[i];
      w1 += (__builtin_popcount((unsigned)(2 * p + 1) & RL) & 1) ? -hp[i] : hp[i];
    }
    const v2f mag = xr[p] * xr[p] + xi[p] * xi[p];
    acc += mag * (v2f){w0, w1};
  }
  float accs = acc.x + acc.y;
  #pragma unroll
  for (int off = 1; off < 64; off <<= 1) accs += __shfl_xor(accs, off, 64);

  if (lane == 0) xacc[w] = accs;
  __syncthreads();
  if (t == 0) out[s] = xacc[0] + xacc[1] + xacc[2] + xacc[3] + hb[0];
}

extern "C" void kernel_launch(void* const* d_in, const int* in_sizes, int n_in,
                              void* d_out, int out_size, void* d_ws, size_t ws_size,
                              hipStream_t stream) {
  const float* sr  = (const float*)d_in[0];
  const float* si  = (const float*)d_in[1];
  const float* wts = (const float*)d_in[2];
  const float* hw  = (const float*)d_in[3];
  const float* hb  = (const float*)d_in[4];
  float* out = (float*)d_out;
  qsim_kernel<<<BATCH, BLK, 0, stream>>>(sr, si, wts, hw, hb, out);
}